// Round 1
// 367.003 us; speedup vs baseline: 1.0187x; 1.0187x over previous
//
#include <hip/hip_runtime.h>

// B=8, Md=256, L=31, N2=286, SHOTS=2, UP=2
// X[b,m,i,l] = sum_s H[b,m,i,l,s] * Y[b,m,i+l,s]   (no wrap: i+l <= 285 < 286)
// out[b,p,q,l] = X[b,p/2,q/2,l] / max(X)
//
// Structure (this round): pass 1 computes X pairs while streaming H, stores X
// to workspace (65 MB, fits L3) and reduces the global max. Pass 2 is a pure
// gather/upsample of X -> 260 MB nontemporal stores. This removes pass 2's
// 130 MB H re-read + recompute + LDS staging that previously sat on its
// critical path.
#define NPAIR 8126464u    // H float4 count = 8*256*256*31*2/4  (== X pair count)

// native clang vector type — required by __builtin_nontemporal_store
typedef float vfloat4 __attribute__((ext_vector_type(4)));

// Pass 1: compute X, store to ws, global max of X.
// H read is a perfectly coalesced float4 stream (130 MB); X2 store is a
// coalesced float2 stream (65 MB, NORMAL stores so X lands in L2/L3 for
// pass 2); Y (4.7 MB) hits cache.
__global__ __launch_bounds__(256) void k_maxX(
    const float4* __restrict__ H4, const float2* __restrict__ Y2,
    int* __restrict__ maxslot, float2* __restrict__ X2)
{
    float m = 0.0f;
    const unsigned stride = gridDim.x * blockDim.x;
    for (unsigned p = blockIdx.x * blockDim.x + threadIdx.x; p < NPAIR; p += stride) {
        unsigned e0 = 2u * p, e1 = e0 + 1u;
        unsigned q0 = e0 / 31u, l0 = e0 - q0 * 31u;   // q = cell (bm*256+i), l
        unsigned q1 = e1 / 31u, l1 = e1 - q1 * 31u;
        unsigned y0 = (q0 >> 8) * 286u + (q0 & 255u) + l0;
        unsigned y1 = (q1 >> 8) * 286u + (q1 & 255u) + l1;
        float4 h = H4[p];
        float2 ya = Y2[y0], yb = Y2[y1];
        float xa = h.x * ya.x + h.y * ya.y;
        float xb = h.z * yb.x + h.w * yb.y;
        X2[p] = make_float2(xa, xb);
        m = fmaxf(m, fmaxf(xa, xb));
    }
    #pragma unroll
    for (int off = 32; off > 0; off >>= 1)
        m = fmaxf(m, __shfl_xor(m, off, 64));
    __shared__ float wmax[4];
    const int lane = threadIdx.x & 63, wid = threadIdx.x >> 6;
    if (lane == 0) wmax[wid] = m;
    __syncthreads();
    if (threadIdx.x == 0) {
        float bmax = fmaxf(fmaxf(wmax[0], wmax[1]), fmaxf(wmax[2], wmax[3]));
        // X >= 0 so int-compare on float bits is order-preserving;
        // ws poison 0xAAAAAAAA is negative => acts as -inf seed.
        atomicMax(maxslot, __float_as_int(bmax));
    }
}

// Pass 2: pure upsample+normalize. Reads X (L3-resident after pass 1),
// writes the 2x2-upsampled output with coalesced nontemporal float4 stores
// (write-once: bypass caches, keep X resident in L3).
// No LDS, no barriers — just ~2 iterations of {4 loads, decode, 2 stores}.
__global__ __launch_bounds__(256) void k_out2(
    const float* __restrict__ X, const int* __restrict__ maxslot,
    vfloat4* __restrict__ out4)
{
    const unsigned bm = blockIdx.x >> 3;     // b*256 + m
    const unsigned ti = blockIdx.x & 7u;     // 1/8 of the output row
    const float inv = 1.0f / __int_as_float(*maxslot);
    const float* __restrict__ Xr = X + bm * 7936u;          // 256*31 floats per bm row

    // out row pair p = 2m, 2m+1; each row = 512*31 floats = 3968 float4
    vfloat4* r0 = out4 + (size_t)((bm >> 8) * 512u + 2u * (bm & 255u)) * 3968u
                       + ti * 496u;
    vfloat4* r1 = r0 + 3968u;   // next output row (identical data)

    for (unsigned g = threadIdx.x; g < 496u; g += 256u) {
        const unsigned sbase = (ti * 496u + g) * 4u;
        vfloat4 v;
        #pragma unroll
        for (int k = 0; k < 4; ++k) {
            unsigned s  = sbase + (unsigned)k;           // float index in out row
            unsigned oc = s / 31u, r = s - oc * 31u;     // out col q, l
            v[k] = Xr[(oc >> 1) * 31u + r] * inv;        // i = q/2
        }
        __builtin_nontemporal_store(v, &r0[g]);
        __builtin_nontemporal_store(v, &r1[g]);
    }
}

extern "C" void kernel_launch(void* const* d_in, const int* in_sizes, int n_in,
                              void* d_out, int out_size, void* d_ws, size_t ws_size,
                              hipStream_t stream) {
    const float* Y = (const float*)d_in[0];   // (8,256,286,2)
    const float* H = (const float*)d_in[1];   // (8,256,256,31,2)

    int* maxslot = (int*)d_ws;                        // poisoned negative = -inf seed
    float2* X2   = (float2*)((char*)d_ws + 256);      // 65,011,712 B; ws ~ 1.04 GB

    k_maxX<<<2048, 256, 0, stream>>>((const float4*)H, (const float2*)Y,
                                     maxslot, X2);
    k_out2<<<8 * 256 * 8, 256, 0, stream>>>((const float*)X2, maxslot,
                                            (vfloat4*)d_out);
}

// Round 3
// 366.432 us; speedup vs baseline: 1.0203x; 1.0016x over previous
//
#include <hip/hip_runtime.h>

// B=8, Md=256, L=31, N2=286, SHOTS=2, UP=2
// X[b,m,i,l] = sum_s H[b,m,i,l,s] * Y[b,m,i+l,s]   (no wrap: i+l <= 285 < 286)
// out[b,p,q,l] = X[b,p/2,q/2,l] / max(X)
//
// Two-kernel structure (verified round 1), re-tuned for memory-level
// parallelism:
//  - k_maxX: exact-trip (16 pairs/thread) unrolled loop -> 4+ H loads in
//    flight per wave instead of 1 -> HBM-saturated instead of latency-bound.
//  - k_out2: one bm-row per block (2048 blocks instead of 16384 micro-blocks),
//    15.5 unrolled iterations/thread -> pipelined NT stores.
#define NPAIR  8126464u   // H float4 count = 8*256*256*31*2/4 (== X pair count)
#define STRIDE1 507904u   // 1984 blocks * 256 threads; 16*STRIDE1 == NPAIR exact

// native clang vector type — required by __builtin_nontemporal_store
typedef float vfloat4 __attribute__((ext_vector_type(4)));

// Pass 1: compute X, store to ws (normal stores -> stays in L2/L3 for pass 2),
// global max of X. H read is a perfectly coalesced float4 stream (130 MB);
// X2 store is a coalesced float2 stream (65 MB); Y (4.7 MB) hits cache.
__global__ __launch_bounds__(256) void k_maxX(
    const float4* __restrict__ H4, const float2* __restrict__ Y2,
    int* __restrict__ maxslot, float2* __restrict__ X2)
{
    float m = 0.0f;
    const unsigned tid = blockIdx.x * 256u + threadIdx.x;
    #pragma unroll 4
    for (unsigned k = 0; k < 16u; ++k) {
        const unsigned p = tid + k * STRIDE1;       // < NPAIR by construction
        unsigned e0 = 2u * p, e1 = e0 + 1u;
        unsigned q0 = e0 / 31u, l0 = e0 - q0 * 31u; // q = cell (bm*256+i), l
        unsigned q1 = e1 / 31u, l1 = e1 - q1 * 31u;
        unsigned y0 = (q0 >> 8) * 286u + (q0 & 255u) + l0;
        unsigned y1 = (q1 >> 8) * 286u + (q1 & 255u) + l1;
        float4 h = H4[p];
        float2 ya = Y2[y0], yb = Y2[y1];
        float xa = h.x * ya.x + h.y * ya.y;
        float xb = h.z * yb.x + h.w * yb.y;
        X2[p] = make_float2(xa, xb);
        m = fmaxf(m, fmaxf(xa, xb));
    }
    #pragma unroll
    for (int off = 32; off > 0; off >>= 1)
        m = fmaxf(m, __shfl_xor(m, off, 64));
    __shared__ float wmax[4];
    const int lane = threadIdx.x & 63, wid = threadIdx.x >> 6;
    if (lane == 0) wmax[wid] = m;
    __syncthreads();
    if (threadIdx.x == 0) {
        float bmax = fmaxf(fmaxf(wmax[0], wmax[1]), fmaxf(wmax[2], wmax[3]));
        // X >= 0 so int-compare on float bits is order-preserving;
        // ws poison 0xAAAAAAAA is negative => acts as -inf seed.
        atomicMax(maxslot, __float_as_int(bmax));
    }
}

// Pass 2: pure upsample+normalize. One block per bm row: reads the row's X
// (L2/L3-resident after pass 1, scalar loads are L1-cached re-reads), writes
// the 2x2-upsampled output rows 2m,2m+1 with coalesced nontemporal float4
// stores (write-once: bypass caches, keep X resident).
__global__ __launch_bounds__(256) void k_out2(
    const float* __restrict__ X, const int* __restrict__ maxslot,
    vfloat4* __restrict__ out4)
{
    const unsigned bm = blockIdx.x;                       // b*256 + m
    const float inv = 1.0f / __int_as_float(*maxslot);
    const float* __restrict__ Xr = X + bm * 7936u;        // 256*31 floats per row

    // out rows p=2m, 2m+1 (identical data); row = 512*31 floats = 3968 float4
    vfloat4* r0 = out4 + (size_t)((bm >> 8) * 512u + 2u * (bm & 255u)) * 3968u;
    vfloat4* r1 = r0 + 3968u;

    #pragma unroll 2
    for (unsigned g = threadIdx.x; g < 3968u; g += 256u) {
        vfloat4 v;
        #pragma unroll
        for (int k = 0; k < 4; ++k) {
            unsigned s  = 4u * g + (unsigned)k;           // float index in out row
            unsigned oc = s / 31u, r = s - oc * 31u;      // out col q, l
            v[k] = Xr[(oc >> 1) * 31u + r] * inv;         // i = q/2
        }
        __builtin_nontemporal_store(v, &r0[g]);
        __builtin_nontemporal_store(v, &r1[g]);
    }
}

extern "C" void kernel_launch(void* const* d_in, const int* in_sizes, int n_in,
                              void* d_out, int out_size, void* d_ws, size_t ws_size,
                              hipStream_t stream) {
    const float* Y = (const float*)d_in[0];   // (8,256,286,2)
    const float* H = (const float*)d_in[1];   // (8,256,256,31,2)

    int* maxslot = (int*)d_ws;                        // poisoned negative = -inf seed
    float2* X2   = (float2*)((char*)d_ws + 256);      // 65,011,712 B; ws ~ 1.04 GB

    k_maxX<<<1984, 256, 0, stream>>>((const float4*)H, (const float2*)Y,
                                     maxslot, X2);
    k_out2<<<2048, 256, 0, stream>>>((const float*)X2, maxslot,
                                     (vfloat4*)d_out);
}

// Round 4
// 365.967 us; speedup vs baseline: 1.0216x; 1.0013x over previous
//
#include <hip/hip_runtime.h>

// B=8, Md=256, L=31, N2=286, SHOTS=2, UP=2
// X[b,m,i,l] = sum_s H[b,m,i,l,s] * Y[b,m,i+l,s]   (no wrap: i+l <= 285 < 286)
// out[b,p,q,l] = X[b,p/2,q/2,l] / max(X)
//
// Minimal-HBM-traffic structure: pass 1 streams H once (130 MB, fills L3)
// computing only the global max; pass 2 recomputes X per bm-row from
// L3-resident H (reads ~free at 34.5 TB/s) and writes the 260 MB output with
// nontemporal stores. No X round trip through HBM.
// Floor: 130 (H) + 260 (out) + 5 (Y) MB ~= 395 MB @ 6.4 TB/s ~= 62 us.
#define NPAIR   8126464u  // H float4 count = 8*256*256*31*2/4
#define STRIDE1  507904u  // 1984 blocks * 256 threads; 16*STRIDE1 == NPAIR exact

// native clang vector type — required by __builtin_nontemporal_store
typedef float vfloat4 __attribute__((ext_vector_type(4)));

// Pass 1: global max of X. Pure coalesced float4 read stream of H (130 MB),
// exact 16 pairs/thread, unrolled -> 4+ loads in flight per wave.
__global__ __launch_bounds__(256) void k_max(
    const float4* __restrict__ H4, const float2* __restrict__ Y2,
    int* __restrict__ maxslot)
{
    float m = 0.0f;
    const unsigned tid = blockIdx.x * 256u + threadIdx.x;
    #pragma unroll 4
    for (unsigned k = 0; k < 16u; ++k) {
        const unsigned p = tid + k * STRIDE1;       // < NPAIR by construction
        unsigned e0 = 2u * p, e1 = e0 + 1u;
        unsigned q0 = e0 / 31u, l0 = e0 - q0 * 31u; // q = cell (bm*256+i), l
        unsigned q1 = e1 / 31u, l1 = e1 - q1 * 31u;
        unsigned y0 = (q0 >> 8) * 286u + (q0 & 255u) + l0;
        unsigned y1 = (q1 >> 8) * 286u + (q1 & 255u) + l1;
        float4 h = H4[p];
        float2 ya = Y2[y0], yb = Y2[y1];
        m = fmaxf(m, fmaxf(h.x * ya.x + h.y * ya.y, h.z * yb.x + h.w * yb.y));
    }
    #pragma unroll
    for (int off = 32; off > 0; off >>= 1)
        m = fmaxf(m, __shfl_xor(m, off, 64));
    __shared__ float wmax[4];
    const int lane = threadIdx.x & 63, wid = threadIdx.x >> 6;
    if (lane == 0) wmax[wid] = m;
    __syncthreads();
    if (threadIdx.x == 0) {
        float bmax = fmaxf(fmaxf(wmax[0], wmax[1]), fmaxf(wmax[2], wmax[3]));
        // X >= 0 so int-compare on float bits is order-preserving;
        // ws poison 0xAAAAAAAA is negative => acts as -inf seed.
        atomicMax(maxslot, __float_as_int(bmax));
    }
}

// Pass 2: one block per bm row. Recompute the row's X (496 float4 H loads,
// L3 hits; Y reads hit L1 — 4.6 KB working set) into LDS, one barrier, then
// 2x2-upsampled normalized output via coalesced nontemporal float4 stores.
// 15.5 iterations per phase -> deep load/store pipelines.
__global__ __launch_bounds__(256) void k_rowout(
    const float4* __restrict__ H4, const float2* __restrict__ Y2,
    const int* __restrict__ maxslot, vfloat4* __restrict__ out4)
{
    __shared__ float xs[7936];                       // one bm row of X (31.75 KB)
    const unsigned bm = blockIdx.x;                  // b*256 + m
    const unsigned t  = threadIdx.x;
    const float inv = 1.0f / __int_as_float(*maxslot);

    const float4* __restrict__ hp = H4 + (size_t)bm * 3968u;  // row's H (63.5 KB)
    const float2* __restrict__ yp = Y2 + (size_t)bm * 286u;   // row's Y (4.6 KB)

    // ---- compute phase: 3968 float4 -> 7936 X floats in LDS ----
    for (unsigned f2 = t; f2 < 3968u; f2 += 256u) {
        unsigned f  = 2u * f2;
        unsigned c0 = f / 31u,        l0 = f        - c0 * 31u;  // cell i, l
        unsigned c1 = (f + 1u) / 31u, l1 = (f + 1u) - c1 * 31u;
        float4 h  = hp[f2];
        float2 ya = yp[c0 + l0];
        float2 yb = yp[c1 + l1];
        xs[f]      = h.x * ya.x + h.y * ya.y;
        xs[f + 1u] = h.z * yb.x + h.w * yb.y;
    }
    __syncthreads();

    // ---- write phase: out rows p=2m,2m+1 (identical); 3968 float4 each ----
    vfloat4* r0 = out4 + (size_t)((bm >> 8) * 512u + 2u * (bm & 255u)) * 3968u;
    vfloat4* r1 = r0 + 3968u;
    #pragma unroll 2
    for (unsigned g = t; g < 3968u; g += 256u) {
        vfloat4 v;
        #pragma unroll
        for (int k = 0; k < 4; ++k) {
            unsigned s  = 4u * g + (unsigned)k;      // float index in out row
            unsigned oc = s / 31u, r = s - oc * 31u; // out col q, l
            v[k] = xs[(oc >> 1) * 31u + r] * inv;    // i = q/2
        }
        __builtin_nontemporal_store(v, &r0[g]);
        __builtin_nontemporal_store(v, &r1[g]);
    }
}

extern "C" void kernel_launch(void* const* d_in, const int* in_sizes, int n_in,
                              void* d_out, int out_size, void* d_ws, size_t ws_size,
                              hipStream_t stream) {
    const float* Y = (const float*)d_in[0];   // (8,256,286,2)
    const float* H = (const float*)d_in[1];   // (8,256,256,31,2)

    int* maxslot = (int*)d_ws;  // poisoned 0xAAAAAAAA (negative) = -inf seed

    k_max<<<1984, 256, 0, stream>>>((const float4*)H, (const float2*)Y, maxslot);
    k_rowout<<<2048, 256, 0, stream>>>((const float4*)H, (const float2*)Y,
                                       maxslot, (vfloat4*)d_out);
}